// Round 8
// baseline (1888.226 us; speedup 1.0000x reference)
//
#include <hip/hip_runtime.h>
#include <hip/hip_bf16.h>

typedef unsigned int u32;
typedef unsigned short u16;

#define N_PTS 100000
#define NSAMP 16

__device__ __forceinline__ float lo2f(u32 u){ return __uint_as_float(u << 16); }
__device__ __forceinline__ float hi2f(u32 u){ return __uint_as_float(u & 0xffff0000u); }
__device__ __forceinline__ float us2f(u16 u){ return __uint_as_float(((u32)u) << 16); }

// Intra-wave LDS ordering fence. WAVEFRONT scope: per the AMDGPU memory
// model this lowers to NO instructions (compiler ordering only). Hardware
// executes one wave's LDS ops in program order, so this is sufficient for
// cross-lane LDS handoff within a single wave64.
// (round-7 lesson: "workgroup" scope drains vmcnt + invalidates L1 on every
// fence -> FETCH_SIZE went 441->819 MB and attn regressed 388->591 us.)
#define WFENCE() __builtin_amdgcn_fence(__ATOMIC_ACQ_REL, "wavefront")

// Runtime input-dtype probe. Reads only EVEN u16 indices (= low halves if the
// buffer is fp32). fp32: low halves decode as bf16 with random exponents ->
// ~46% exceed 1024 in magnitude. bf16 N(0,1): zero hits.
// Must be called by ALL threads of the block (contains a barrier).
__device__ __forceinline__ bool detect_f32(const u16* __restrict__ xprobe) {
    float f = us2f(xprobe[(threadIdx.x & 63) * 2]);
    int cnt = __syncthreads_count(fabsf(f) > 1024.0f ? 1 : 0);
    return cnt >= 8;
}

// canonical fp32 weight-block offsets (floats, each 16B-aligned)
#define OFF_WQ   0
#define OFF_BQ   4096
#define OFF_WK   4160
#define OFF_BK   8256
#define OFF_WV   8320
#define OFF_BV   12416
#define OFF_WP1  12480
#define OFF_BP1  12492
#define OFF_GP   12496
#define OFF_BP   12500
#define OFF_WP2  12504
#define OFF_BP2  12696
#define OFF_G1   12760
#define OFF_BB1  12824
#define OFF_WA   12888
#define OFF_BA   13400
#define OFF_G2   13408
#define OFF_BB2  13416
#define OFF_WB   13424
#define OFF_BW   13488
#define CW_PAD   16384   /* pad region to 64 KB of floats */

// ---------------------------------------------------------------------------
// K0: canonicalize all small weight arrays to fp32 (handles bf16 or fp32 src)
// ---------------------------------------------------------------------------
__global__ __launch_bounds__(256) void convert_kernel(
    const u16* __restrict__ xprobe,
    const void* s0,  const void* s1,  const void* s2,  const void* s3,
    const void* s4,  const void* s5,  const void* s6,  const void* s7,
    const void* s8,  const void* s9,  const void* s10, const void* s11,
    const void* s12, const void* s13, const void* s14, const void* s15,
    const void* s16, const void* s17, const void* s18, const void* s19,
    float* __restrict__ cw)
{
    bool isf32 = detect_f32(xprobe);
    const void* srcs[20] = {s0,s1,s2,s3,s4,s5,s6,s7,s8,s9,s10,s11,s12,s13,s14,s15,s16,s17,s18,s19};
    const int sizes[20] = {4096,64,4096,64,4096,64,9,3,3,3,192,64,64,64,512,8,8,8,64,8};
    const int offs[20]  = {OFF_WQ,OFF_BQ,OFF_WK,OFF_BK,OFF_WV,OFF_BV,OFF_WP1,OFF_BP1,OFF_GP,OFF_BP,
                           OFF_WP2,OFF_BP2,OFF_G1,OFF_BB1,OFF_WA,OFF_BA,OFF_G2,OFF_BB2,OFF_WB,OFF_BW};
    int tid = threadIdx.x + blockIdx.x * 256;
    int stride = gridDim.x * 256;
    for (int a = 0; a < 20; a++) {
        const void* s = srcs[a];
        for (int k = tid; k < sizes[a]; k += stride)
            cw[offs[a] + k] = isf32 ? ((const float*)s)[k] : us2f(((const u16*)s)[k]);
    }
}

// ---------------------------------------------------------------------------
// K1: Q/K/V projection — LDS-staged x tile + fused 3-matrix k-loop.
// Block 256 = 64-row tile. Stage x[64][64] in LDS once (coalesced), then
// thread (rq = tid>>4, cq = tid&15) computes 4 rows x 4 cols for ALL THREE
// matrices in one k-sweep: x from LDS (ds_read_b128), W from global
// (L1-hot, every block reads the same 48 KB in the same order).
// Per-(matrix,row,col) accumulation order: bias then k ascending —
// bitwise-identical to the trusted round-4..7 kernels.
// ---------------------------------------------------------------------------
__global__ __launch_bounds__(256) void qkv_kernel(
    const u16* __restrict__ xraw, const float* __restrict__ cw,
    float* __restrict__ Q, float* __restrict__ K, float* __restrict__ V)
{
    __shared__ __align__(16) float xs[64][68];   // 64 rows x 64 k, stride 68

    bool isf32 = detect_f32(xraw);
    const int tid = threadIdx.x;
    const long rbase = (long)blockIdx.x * 64;

    // ---- stage x tile: thread -> (row = tid>>2, 16-float segment = tid&3) ----
    {
        const int r   = tid >> 2;
        const int seg = (tid & 3) * 16;
        long gr = rbase + r; if (gr >= N_PTS) gr = N_PTS - 1;   // clamp (tail)
        if (isf32) {
            const float* src = (const float*)xraw + (size_t)gr * 64 + seg;
            float4 a = ((const float4*)src)[0];
            float4 b = ((const float4*)src)[1];
            float4 c = ((const float4*)src)[2];
            float4 d = ((const float4*)src)[3];
            *((float4*)&xs[r][seg + 0])  = a;
            *((float4*)&xs[r][seg + 4])  = b;
            *((float4*)&xs[r][seg + 8])  = c;
            *((float4*)&xs[r][seg + 12]) = d;
        } else {
            const u16* src = xraw + (size_t)gr * 64 + seg;
#pragma unroll
            for (int t = 0; t < 16; t++) xs[r][seg + t] = us2f(src[t]);
        }
    }
    __syncthreads();

    const int cq = tid & 15;
    const int rq = tid >> 4;
    const int c0 = cq * 4;
    const int r0 = rq * 4;

    const float* wqp = cw + OFF_WQ + c0;
    const float* wkp = cw + OFF_WK + c0;
    const float* wvp = cw + OFF_WV + c0;

    float acc[3][4][4];
    {
        float4 bq = *((const float4*)(cw + OFF_BQ + c0));
        float4 bk = *((const float4*)(cw + OFF_BK + c0));
        float4 bv = *((const float4*)(cw + OFF_BV + c0));
#pragma unroll
        for (int rr = 0; rr < 4; rr++) {
            acc[0][rr][0] = bq.x; acc[0][rr][1] = bq.y; acc[0][rr][2] = bq.z; acc[0][rr][3] = bq.w;
            acc[1][rr][0] = bk.x; acc[1][rr][1] = bk.y; acc[1][rr][2] = bk.z; acc[1][rr][3] = bk.w;
            acc[2][rr][0] = bv.x; acc[2][rr][1] = bv.y; acc[2][rr][2] = bv.z; acc[2][rr][3] = bv.w;
        }
    }

#pragma unroll
    for (int k4 = 0; k4 < 16; k4++) {
        const int k = k4 * 4;
        float x4[4][4];
#pragma unroll
        for (int rr = 0; rr < 4; rr++) {
            float4 t = *((const float4*)&xs[r0 + rr][k]);
            x4[rr][0] = t.x; x4[rr][1] = t.y; x4[rr][2] = t.z; x4[rr][3] = t.w;
        }
#pragma unroll
        for (int kk = 0; kk < 4; kk++) {
            float4 wq4 = *((const float4*)(wqp + (size_t)(k + kk) * 64));
            float4 wk4 = *((const float4*)(wkp + (size_t)(k + kk) * 64));
            float4 wv4 = *((const float4*)(wvp + (size_t)(k + kk) * 64));
#pragma unroll
            for (int rr = 0; rr < 4; rr++) {
                float xv = x4[rr][kk];
                acc[0][rr][0] = fmaf(xv, wq4.x, acc[0][rr][0]);
                acc[0][rr][1] = fmaf(xv, wq4.y, acc[0][rr][1]);
                acc[0][rr][2] = fmaf(xv, wq4.z, acc[0][rr][2]);
                acc[0][rr][3] = fmaf(xv, wq4.w, acc[0][rr][3]);
                acc[1][rr][0] = fmaf(xv, wk4.x, acc[1][rr][0]);
                acc[1][rr][1] = fmaf(xv, wk4.y, acc[1][rr][1]);
                acc[1][rr][2] = fmaf(xv, wk4.z, acc[1][rr][2]);
                acc[1][rr][3] = fmaf(xv, wk4.w, acc[1][rr][3]);
                acc[2][rr][0] = fmaf(xv, wv4.x, acc[2][rr][0]);
                acc[2][rr][1] = fmaf(xv, wv4.y, acc[2][rr][1]);
                acc[2][rr][2] = fmaf(xv, wv4.z, acc[2][rr][2]);
                acc[2][rr][3] = fmaf(xv, wv4.w, acc[2][rr][3]);
            }
        }
    }

#pragma unroll
    for (int rr = 0; rr < 4; rr++) {
        long gr = rbase + r0 + rr;
        if (gr < N_PTS) {
            *((float4*)(Q + (size_t)gr * 64 + c0)) =
                make_float4(acc[0][rr][0], acc[0][rr][1], acc[0][rr][2], acc[0][rr][3]);
            *((float4*)(K + (size_t)gr * 64 + c0)) =
                make_float4(acc[1][rr][0], acc[1][rr][1], acc[1][rr][2], acc[1][rr][3]);
            *((float4*)(V + (size_t)gr * 64 + c0)) =
                make_float4(acc[2][rr][0], acc[2][rr][1], acc[2][rr][2], acc[2][rr][3]);
        }
    }
}

// ---------------------------------------------------------------------------
// K2: fused attention — persistent grid-stride, ONE WAVE PER POINT, fully
// independent waves (no __syncthreads in the loop; WFENCE = wavefront scope,
// zero instructions). Lane = channel c. LDS slices are wave-private; WaT
// (transposed Wa) shared, preloaded once. Stage math/order identical to the
// trusted round-4 kernel.
// ---------------------------------------------------------------------------
__global__ __launch_bounds__(256, 6) void attn_kernel(
    const u16* __restrict__ P, const int* __restrict__ IDX,
    const u16* __restrict__ xprobe, const float* __restrict__ cw,
    const float* __restrict__ Q, const float* __restrict__ K,
    const float* __restrict__ V, void* __restrict__ OUT)
{
    __shared__ __align__(16) float wvb[4][16 * 68];  // per-wave wv (stride 68); [0..127] reused as w2
    __shared__ __align__(16) float tbb[4][128];      // per-wave tb
    __shared__ __align__(16) float waT[8 * 68];      // Wa transposed [s][c], stride 68

    bool isf32 = detect_f32(xprobe);

    const int tid = threadIdx.x;
    // preload WaT: waT[s][c] = Wa[c][s] — all 512 entries (2 per thread)
    for (int t = tid; t < 512; t += 256) {
        int cc = t >> 3, ss = t & 7;
        waT[ss * 68 + cc] = cw[OFF_WA + cc * 8 + ss];
    }
    __syncthreads();   // once, before the loop

    const int wid = tid >> 6;
    const int c   = tid & 63;
    float* wvs = wvb[wid];
    float* tbs = tbb[wid];
    const float rs = 1.0f / sqrtf(1.0f + 1e-5f);

    // ---- hoisted per-lane constants (loaded once per block) ----
    const int s8 = c & 7;              // this lane's attention channel (stages 2/3/5)
    const int n0 = c >> 3;             // this lane's first neighbor row (stages 2/3)
    const float ba_s  = cw[OFF_BA  + s8];
    const float g2_s  = cw[OFF_G2  + s8] * rs;
    const float bb2_s = cw[OFF_BB2 + s8];
    const float bw_t  = cw[OFF_BW  + s8];
    float wbcol[8];
#pragma unroll
    for (int s = 0; s < 8; s++) wbcol[s] = cw[OFF_WB + s * 8 + s8];

    const float wp2c0 = cw[OFF_WP2 + 0 * 64 + c];
    const float wp2c1 = cw[OFF_WP2 + 1 * 64 + c];
    const float wp2c2 = cw[OFF_WP2 + 2 * 64 + c];
    const float bp2c  = cw[OFF_BP2 + c];
    const float g1c   = cw[OFF_G1  + c] * rs;
    const float bb1c  = cw[OFF_BB1 + c];
    float wp1f[9], bp1f[3];
#pragma unroll
    for (int d = 0; d < 3; d++) {
        float gd = cw[OFF_GP + d] * rs;
#pragma unroll
        for (int e = 0; e < 3; e++) wp1f[e * 3 + d] = cw[OFF_WP1 + e * 3 + d] * gd;
        bp1f[d] = cw[OFF_BP1 + d] * gd + cw[OFF_BP + d];
    }

    const float* Pf = (const float*)P;
    const int wstride = gridDim.x * 4;

    for (int i = blockIdx.x * 4 + wid; i < N_PTS; i += wstride) {
        float pi0, pi1, pi2;
        if (isf32) { pi0 = Pf[i*3+0]; pi1 = Pf[i*3+1]; pi2 = Pf[i*3+2]; }
        else       { pi0 = us2f(P[i*3+0]); pi1 = us2f(P[i*3+1]); pi2 = us2f(P[i*3+2]); }
        const float qq = Q[(size_t)i * 64 + c];
        float pv[NSAMP];

        // ---- stage 1: per-(n,c) relation input into LDS; v+pe in regs ----
#pragma unroll
        for (int n = 0; n < NSAMP; n++) {
            const int j = IDX[i * NSAMP + n];
            float pr0, pr1, pr2;
            if (isf32) {
                pr0 = Pf[j*3+0] - pi0; pr1 = Pf[j*3+1] - pi1; pr2 = Pf[j*3+2] - pi2;
            } else {
                pr0 = us2f(P[j*3+0]) - pi0; pr1 = us2f(P[j*3+1]) - pi1; pr2 = us2f(P[j*3+2]) - pi2;
            }
            float h0 = fmaxf(fmaf(pr2, wp1f[6], fmaf(pr1, wp1f[3], fmaf(pr0, wp1f[0], bp1f[0]))), 0.0f);
            float h1 = fmaxf(fmaf(pr2, wp1f[7], fmaf(pr1, wp1f[4], fmaf(pr0, wp1f[1], bp1f[1]))), 0.0f);
            float h2 = fmaxf(fmaf(pr2, wp1f[8], fmaf(pr1, wp1f[5], fmaf(pr0, wp1f[2], bp1f[2]))), 0.0f);
            float pe = fmaf(h2, wp2c2, fmaf(h1, wp2c1, fmaf(h0, wp2c0, bp2c)));
            float kk = K[(size_t)j * 64 + c];
            float vv = V[(size_t)j * 64 + c];
            wvs[n * 68 + c] = fmaxf(fmaf(kk - qq + pe, g1c, bb1c), 0.0f);
            pv[n] = vv + pe;
        }
        WFENCE();

        // ---- stage 2: a[n][s] = ba[s] + sum_c wv[n][c]*Wa[c][s] for this
        // lane's two rows (n0, n0+8), shared column s8 of WaT ----
        float a0 = ba_s, a1 = ba_s;
#pragma unroll
        for (int c4 = 0; c4 < 16; c4++) {
            float4 wa = *((const float4*)&waT[s8 * 68 + c4 * 4]);
            float4 w0 = *((const float4*)&wvs[n0 * 68 + c4 * 4]);
            float4 w1 = *((const float4*)&wvs[(n0 + 8) * 68 + c4 * 4]);
            a0 = fmaf(w0.x, wa.x, a0); a0 = fmaf(w0.y, wa.y, a0);
            a0 = fmaf(w0.z, wa.z, a0); a0 = fmaf(w0.w, wa.w, a0);
            a1 = fmaf(w1.x, wa.x, a1); a1 = fmaf(w1.y, wa.y, a1);
            a1 = fmaf(w1.z, wa.z, a1); a1 = fmaf(w1.w, wa.w, a1);
        }
        tbs[n0 * 8 + s8]       = fmaxf(fmaf(a0, g2_s, bb2_s), 0.0f);
        tbs[(n0 + 8) * 8 + s8] = fmaxf(fmaf(a1, g2_s, bb2_s), 0.0f);
        WFENCE();

        // ---- stage 3: logits w2[n][t] = bw[t] + sum_s tb[n][s]*Wb[s][t];
        // stored into wvs[0..127] (wv no longer needed) ----
        float w2a = bw_t, w2b = bw_t;
#pragma unroll
        for (int s = 0; s < 8; s++) {
            w2a = fmaf(tbs[n0 * 8 + s],       wbcol[s], w2a);
            w2b = fmaf(tbs[(n0 + 8) * 8 + s], wbcol[s], w2b);
        }
        wvs[n0 * 8 + s8]       = w2a;
        wvs[(n0 + 8) * 8 + s8] = w2b;
        WFENCE();

        // ---- stage 4: softmax over neighbors per channel t (lanes 0..7) ----
        if (c < 8) {
            float mx = -1e30f;
#pragma unroll
            for (int n = 0; n < NSAMP; n++) mx = fmaxf(mx, wvs[n * 8 + c]);
            float sm = 0.0f;
            float e[NSAMP];
#pragma unroll
            for (int n = 0; n < NSAMP; n++) { e[n] = __expf(wvs[n * 8 + c] - mx); sm += e[n]; }
            float inv = 1.0f / sm;
#pragma unroll
            for (int n = 0; n < NSAMP; n++) wvs[n * 8 + c] = e[n] * inv;
        }
        WFENCE();

        // ---- stage 5: out[c] = sum_n pv[n] * w[n][c&7] ----
        float o = 0.0f;
#pragma unroll
        for (int n = 0; n < NSAMP; n++)
            o = fmaf(pv[n], wvs[n * 8 + s8], o);
        if (isf32) ((float*)OUT)[(size_t)i * 64 + c] = o;
        else       ((__hip_bfloat16*)OUT)[(size_t)i * 64 + c] = __float2bfloat16(o);
        WFENCE();   // protect wvs before next iteration's stage-1 writes
    }
}

// ---------------------------------------------------------------------------
extern "C" void kernel_launch(void* const* d_in, const int* in_sizes, int n_in,
                              void* d_out, int out_size, void* d_ws, size_t ws_size,
                              hipStream_t stream)
{
    const u16* p   = (const u16*)d_in[0];
    const u16* x   = (const u16*)d_in[1];
    const int* idx = (const int*)d_in[2];

    // workspace layout (76.9 MB — proven safe)
    float* cw = (float*)d_ws;                 // 64 KB
    float* Q  = cw + CW_PAD;                  // N*64 f32 = 25.6 MB
    float* K  = Q + (size_t)N_PTS * 64;       // 25.6 MB
    float* V  = K + (size_t)N_PTS * 64;       // 25.6 MB

    convert_kernel<<<8, 256, 0, stream>>>(
        x,
        d_in[3],  d_in[4],  d_in[5],  d_in[6],  d_in[7],  d_in[8],
        d_in[9],  d_in[10], d_in[11], d_in[12], d_in[13], d_in[14],
        d_in[15], d_in[16], d_in[17], d_in[18], d_in[19], d_in[20],
        d_in[21], d_in[22], cw);
    qkv_kernel<<<1563, 256, 0, stream>>>(x, cw, Q, K, V);      // 1563*64 >= 100000
    attn_kernel<<<1792, 256, 0, stream>>>(p, idx, x, cw, Q, K, V, d_out);
}

// Round 9
// 682.535 us; speedup vs baseline: 2.7665x; 2.7665x over previous
//
#include <hip/hip_runtime.h>
#include <hip/hip_bf16.h>

typedef unsigned int u32;
typedef unsigned short u16;

#define N_PTS 100000
#define NSAMP 16

__device__ __forceinline__ float lo2f(u32 u){ return __uint_as_float(u << 16); }
__device__ __forceinline__ float hi2f(u32 u){ return __uint_as_float(u & 0xffff0000u); }
__device__ __forceinline__ float us2f(u16 u){ return __uint_as_float(((u32)u) << 16); }

// Runtime input-dtype probe. Reads only EVEN u16 indices (= low halves if the
// buffer is fp32). fp32: low halves decode as bf16 with random exponents ->
// ~46% exceed 1024 in magnitude. bf16 N(0,1): zero hits.
// Must be called by ALL threads of the block (contains a barrier).
__device__ __forceinline__ bool detect_f32(const u16* __restrict__ xprobe) {
    float f = us2f(xprobe[(threadIdx.x & 63) * 2]);
    int cnt = __syncthreads_count(fabsf(f) > 1024.0f ? 1 : 0);
    return cnt >= 8;
}

// canonical fp32 weight-block offsets (floats, each 16B-aligned)
#define OFF_WQ   0
#define OFF_BQ   4096
#define OFF_WK   4160
#define OFF_BK   8256
#define OFF_WV   8320
#define OFF_BV   12416
#define OFF_WP1  12480
#define OFF_BP1  12492
#define OFF_GP   12496
#define OFF_BP   12500
#define OFF_WP2  12504
#define OFF_BP2  12696
#define OFF_G1   12760
#define OFF_BB1  12824
#define OFF_WA   12888
#define OFF_BA   13400
#define OFF_G2   13408
#define OFF_BB2  13416
#define OFF_WB   13424
#define OFF_BW   13488
#define CW_PAD   16384   /* pad region to 64 KB of floats */

// ---------------------------------------------------------------------------
// K0: canonicalize all small weight arrays to fp32 (handles bf16 or fp32 src)
// ---------------------------------------------------------------------------
__global__ __launch_bounds__(256) void convert_kernel(
    const u16* __restrict__ xprobe,
    const void* s0,  const void* s1,  const void* s2,  const void* s3,
    const void* s4,  const void* s5,  const void* s6,  const void* s7,
    const void* s8,  const void* s9,  const void* s10, const void* s11,
    const void* s12, const void* s13, const void* s14, const void* s15,
    const void* s16, const void* s17, const void* s18, const void* s19,
    float* __restrict__ cw)
{
    bool isf32 = detect_f32(xprobe);
    const void* srcs[20] = {s0,s1,s2,s3,s4,s5,s6,s7,s8,s9,s10,s11,s12,s13,s14,s15,s16,s17,s18,s19};
    const int sizes[20] = {4096,64,4096,64,4096,64,9,3,3,3,192,64,64,64,512,8,8,8,64,8};
    const int offs[20]  = {OFF_WQ,OFF_BQ,OFF_WK,OFF_BK,OFF_WV,OFF_BV,OFF_WP1,OFF_BP1,OFF_GP,OFF_BP,
                           OFF_WP2,OFF_BP2,OFF_G1,OFF_BB1,OFF_WA,OFF_BA,OFF_G2,OFF_BB2,OFF_WB,OFF_BW};
    int tid = threadIdx.x + blockIdx.x * 256;
    int stride = gridDim.x * 256;
    for (int a = 0; a < 20; a++) {
        const void* s = srcs[a];
        for (int k = tid; k < sizes[a]; k += stride)
            cw[offs[a] + k] = isf32 ? ((const float*)s)[k] : us2f(((const u16*)s)[k]);
    }
}

// ---------------------------------------------------------------------------
// K1: Q/K/V projection — LDS-staged x tile, matrices SEQUENTIAL (acc=16 regs;
// round-8 lesson: the fused 3-matrix loop + full unroll hit 256 VGPRs and
// spilled 3.1 GB to scratch). W via L1 (every block reads the same 48 KB).
// __launch_bounds__(256,4) caps VGPRs at 128; k-loop unroll limited to 4.
// Per-(matrix,row,col) accumulation order: bias then k ascending —
// bitwise-identical to the trusted kernels.
// ---------------------------------------------------------------------------
__global__ __launch_bounds__(256, 4) void qkv_kernel(
    const u16* __restrict__ xraw, const float* __restrict__ cw,
    float* __restrict__ Q, float* __restrict__ K, float* __restrict__ V)
{
    __shared__ __align__(16) float xs[64][68];   // 64 rows x 64 k, stride 68

    bool isf32 = detect_f32(xraw);
    const int tid = threadIdx.x;
    const long rbase = (long)blockIdx.x * 64;

    // ---- stage x tile: thread -> (row = tid>>2, 16-float segment = tid&3) ----
    {
        const int r   = tid >> 2;
        const int seg = (tid & 3) * 16;
        long gr = rbase + r; if (gr >= N_PTS) gr = N_PTS - 1;   // clamp (tail)
        if (isf32) {
            const float* src = (const float*)xraw + (size_t)gr * 64 + seg;
            float4 a = ((const float4*)src)[0];
            float4 b = ((const float4*)src)[1];
            float4 c = ((const float4*)src)[2];
            float4 d = ((const float4*)src)[3];
            *((float4*)&xs[r][seg + 0])  = a;
            *((float4*)&xs[r][seg + 4])  = b;
            *((float4*)&xs[r][seg + 8])  = c;
            *((float4*)&xs[r][seg + 12]) = d;
        } else {
            const u16* src = xraw + (size_t)gr * 64 + seg;
#pragma unroll
            for (int t = 0; t < 16; t++) xs[r][seg + t] = us2f(src[t]);
        }
    }
    __syncthreads();

    const int cq = tid & 15;
    const int rq = tid >> 4;
    const int c0 = cq * 4;
    const int r0 = rq * 4;

    for (int m = 0; m < 3; m++) {
        const float* W = cw + (m == 0 ? OFF_WQ : (m == 1 ? OFF_WK : OFF_WV)) + c0;
        const float* B = cw + (m == 0 ? OFF_BQ : (m == 1 ? OFF_BK : OFF_BV));
        float* O = (m == 0) ? Q : ((m == 1) ? K : V);

        float4 b4 = *((const float4*)(B + c0));
        float acc[4][4];
#pragma unroll
        for (int rr = 0; rr < 4; rr++) {
            acc[rr][0] = b4.x; acc[rr][1] = b4.y; acc[rr][2] = b4.z; acc[rr][3] = b4.w;
        }

#pragma unroll 4
        for (int k4 = 0; k4 < 16; k4++) {
            const int k = k4 * 4;
            float x4[4][4];
#pragma unroll
            for (int rr = 0; rr < 4; rr++) {
                float4 t = *((const float4*)&xs[r0 + rr][k]);
                x4[rr][0] = t.x; x4[rr][1] = t.y; x4[rr][2] = t.z; x4[rr][3] = t.w;
            }
#pragma unroll
            for (int kk = 0; kk < 4; kk++) {
                float4 w4 = *((const float4*)(W + (size_t)(k + kk) * 64));
#pragma unroll
                for (int rr = 0; rr < 4; rr++) {
                    acc[rr][0] = fmaf(x4[rr][kk], w4.x, acc[rr][0]);
                    acc[rr][1] = fmaf(x4[rr][kk], w4.y, acc[rr][1]);
                    acc[rr][2] = fmaf(x4[rr][kk], w4.z, acc[rr][2]);
                    acc[rr][3] = fmaf(x4[rr][kk], w4.w, acc[rr][3]);
                }
            }
        }
#pragma unroll
        for (int rr = 0; rr < 4; rr++) {
            long gr = rbase + r0 + rr;
            if (gr < N_PTS) {
                *((float4*)(O + (size_t)gr * 64 + c0)) =
                    make_float4(acc[rr][0], acc[rr][1], acc[rr][2], acc[rr][3]);
            }
        }
    }
}

// ---------------------------------------------------------------------------
// K2: fused attention — persistent 128-thread blocks = 2 waves, each wave an
// independent point stream with its own LDS slice; REAL __syncthreads (4 per
// point; rounds 7/8 showed fence tricks regress). Uniform trip count so
// barriers are safe. waT staged once per block; weights hoisted once.
// Stage math/order identical to the trusted round-4/7 kernels.
// Softmax weights routed via tbs so stage 5 + next stage 1 need no barrier.
// ---------------------------------------------------------------------------
__global__ __launch_bounds__(128, 6) void attn_kernel(
    const u16* __restrict__ P, const int* __restrict__ IDX,
    const u16* __restrict__ xprobe, const float* __restrict__ cw,
    const float* __restrict__ Q, const float* __restrict__ K,
    const float* __restrict__ V, void* __restrict__ OUT)
{
    __shared__ __align__(16) float wvb[2][16 * 68];  // per-wave wv (stride 68); [0..127] reused as logits
    __shared__ __align__(16) float tbb[2][128];      // per-wave tb, then softmax weights
    __shared__ __align__(16) float waT[8 * 68];      // Wa transposed [s][c], stride 68

    bool isf32 = detect_f32(xprobe);

    const int tid = threadIdx.x;
    // preload WaT: waT[s][c] = Wa[c][s] — all 512 entries (4 per thread)
    for (int t = tid; t < 512; t += 128) {
        int cc = t >> 3, ss = t & 7;
        waT[ss * 68 + cc] = cw[OFF_WA + cc * 8 + ss];
    }
    __syncthreads();

    const int wid = tid >> 6;          // wave 0/1 = independent point stream
    const int c   = tid & 63;
    float* wvs = wvb[wid];
    float* tbs = tbb[wid];
    const float rs = 1.0f / sqrtf(1.0f + 1e-5f);

    // ---- hoisted per-lane constants (loaded once per block) ----
    const int s8 = c & 7;              // this lane's attention channel
    const int n0 = c >> 3;             // this lane's first neighbor row
    const float ba_s  = cw[OFF_BA  + s8];
    const float g2_s  = cw[OFF_G2  + s8] * rs;
    const float bb2_s = cw[OFF_BB2 + s8];
    const float bw_t  = cw[OFF_BW  + s8];
    float wbcol[8];
#pragma unroll
    for (int s = 0; s < 8; s++) wbcol[s] = cw[OFF_WB + s * 8 + s8];

    const float wp2c0 = cw[OFF_WP2 + 0 * 64 + c];
    const float wp2c1 = cw[OFF_WP2 + 1 * 64 + c];
    const float wp2c2 = cw[OFF_WP2 + 2 * 64 + c];
    const float bp2c  = cw[OFF_BP2 + c];
    const float g1c   = cw[OFF_G1  + c] * rs;
    const float bb1c  = cw[OFF_BB1 + c];
    float wp1f[9], bp1f[3];
#pragma unroll
    for (int d = 0; d < 3; d++) {
        float gd = cw[OFF_GP + d] * rs;
#pragma unroll
        for (int e = 0; e < 3; e++) wp1f[e * 3 + d] = cw[OFF_WP1 + e * 3 + d] * gd;
        bp1f[d] = cw[OFF_BP1 + d] * gd + cw[OFF_BP + d];
    }

    const float* Pf = (const float*)P;
    const int wstride = gridDim.x * 2;                       // waves in grid
    const int iters = (N_PTS + wstride - 1) / wstride;       // uniform trip count

    for (int it = 0; it < iters; it++) {
        const int i = blockIdx.x * 2 + wid + it * wstride;
        const bool act = (i < N_PTS);
        float pv[NSAMP];

        // ---- stage 1: per-(n,c) relation input into LDS; v+pe in regs ----
        if (act) {
            float pi0, pi1, pi2;
            if (isf32) { pi0 = Pf[i*3+0]; pi1 = Pf[i*3+1]; pi2 = Pf[i*3+2]; }
            else       { pi0 = us2f(P[i*3+0]); pi1 = us2f(P[i*3+1]); pi2 = us2f(P[i*3+2]); }
            const float qq = Q[(size_t)i * 64 + c];
#pragma unroll
            for (int n = 0; n < NSAMP; n++) {
                const int j = IDX[i * NSAMP + n];
                float pr0, pr1, pr2;
                if (isf32) {
                    pr0 = Pf[j*3+0] - pi0; pr1 = Pf[j*3+1] - pi1; pr2 = Pf[j*3+2] - pi2;
                } else {
                    pr0 = us2f(P[j*3+0]) - pi0; pr1 = us2f(P[j*3+1]) - pi1; pr2 = us2f(P[j*3+2]) - pi2;
                }
                float h0 = fmaxf(fmaf(pr2, wp1f[6], fmaf(pr1, wp1f[3], fmaf(pr0, wp1f[0], bp1f[0]))), 0.0f);
                float h1 = fmaxf(fmaf(pr2, wp1f[7], fmaf(pr1, wp1f[4], fmaf(pr0, wp1f[1], bp1f[1]))), 0.0f);
                float h2 = fmaxf(fmaf(pr2, wp1f[8], fmaf(pr1, wp1f[5], fmaf(pr0, wp1f[2], bp1f[2]))), 0.0f);
                float pe = fmaf(h2, wp2c2, fmaf(h1, wp2c1, fmaf(h0, wp2c0, bp2c)));
                float kk = K[(size_t)j * 64 + c];
                float vv = V[(size_t)j * 64 + c];
                wvs[n * 68 + c] = fmaxf(fmaf(kk - qq + pe, g1c, bb1c), 0.0f);
                pv[n] = vv + pe;
            }
        }
        __syncthreads();

        // ---- stage 2: a[n][s] = ba[s] + sum_c wv[n][c]*Wa[c][s] (2 rows/lane) ----
        {
            float a0 = ba_s, a1 = ba_s;
#pragma unroll
            for (int c4 = 0; c4 < 16; c4++) {
                float4 wa = *((const float4*)&waT[s8 * 68 + c4 * 4]);
                float4 w0 = *((const float4*)&wvs[n0 * 68 + c4 * 4]);
                float4 w1 = *((const float4*)&wvs[(n0 + 8) * 68 + c4 * 4]);
                a0 = fmaf(w0.x, wa.x, a0); a0 = fmaf(w0.y, wa.y, a0);
                a0 = fmaf(w0.z, wa.z, a0); a0 = fmaf(w0.w, wa.w, a0);
                a1 = fmaf(w1.x, wa.x, a1); a1 = fmaf(w1.y, wa.y, a1);
                a1 = fmaf(w1.z, wa.z, a1); a1 = fmaf(w1.w, wa.w, a1);
            }
            tbs[n0 * 8 + s8]       = fmaxf(fmaf(a0, g2_s, bb2_s), 0.0f);
            tbs[(n0 + 8) * 8 + s8] = fmaxf(fmaf(a1, g2_s, bb2_s), 0.0f);
        }
        __syncthreads();

        // ---- stage 3: logits w2[n][t] = bw[t] + sum_s tb[n][s]*Wb[s][t]
        //      -> wvs[0..127] ----
        {
            float w2a = bw_t, w2b = bw_t;
#pragma unroll
            for (int s = 0; s < 8; s++) {
                w2a = fmaf(tbs[n0 * 8 + s],       wbcol[s], w2a);
                w2b = fmaf(tbs[(n0 + 8) * 8 + s], wbcol[s], w2b);
            }
            wvs[n0 * 8 + s8]       = w2a;
            wvs[(n0 + 8) * 8 + s8] = w2b;
        }
        __syncthreads();

        // ---- stage 4: softmax over neighbors per channel (lanes 0..7);
        //      weights stored into tbs (tb values dead) ----
        if (c < 8) {
            float mx = -1e30f;
#pragma unroll
            for (int n = 0; n < NSAMP; n++) mx = fmaxf(mx, wvs[n * 8 + c]);
            float sm = 0.0f;
            float e[NSAMP];
#pragma unroll
            for (int n = 0; n < NSAMP; n++) { e[n] = __expf(wvs[n * 8 + c] - mx); sm += e[n]; }
            float inv = 1.0f / sm;
#pragma unroll
            for (int n = 0; n < NSAMP; n++) tbs[n * 8 + c] = e[n] * inv;
        }
        __syncthreads();

        // ---- stage 5: out[c] = sum_n pv[n] * w[n][c&7] (reads tbs only;
        //      next iteration's stage 1 touches only wvs -> no barrier) ----
        if (act) {
            float o = 0.0f;
#pragma unroll
            for (int n = 0; n < NSAMP; n++)
                o = fmaf(pv[n], tbs[n * 8 + s8], o);
            if (isf32) ((float*)OUT)[(size_t)i * 64 + c] = o;
            else       ((__hip_bfloat16*)OUT)[(size_t)i * 64 + c] = __float2bfloat16(o);
        }
    }
}

// ---------------------------------------------------------------------------
extern "C" void kernel_launch(void* const* d_in, const int* in_sizes, int n_in,
                              void* d_out, int out_size, void* d_ws, size_t ws_size,
                              hipStream_t stream)
{
    const u16* p   = (const u16*)d_in[0];
    const u16* x   = (const u16*)d_in[1];
    const int* idx = (const int*)d_in[2];

    // workspace layout (76.9 MB — proven safe)
    float* cw = (float*)d_ws;                 // 64 KB
    float* Q  = cw + CW_PAD;                  // N*64 f32 = 25.6 MB
    float* K  = Q + (size_t)N_PTS * 64;       // 25.6 MB
    float* V  = K + (size_t)N_PTS * 64;       // 25.6 MB

    convert_kernel<<<8, 256, 0, stream>>>(
        x,
        d_in[3],  d_in[4],  d_in[5],  d_in[6],  d_in[7],  d_in[8],
        d_in[9],  d_in[10], d_in[11], d_in[12], d_in[13], d_in[14],
        d_in[15], d_in[16], d_in[17], d_in[18], d_in[19], d_in[20],
        d_in[21], d_in[22], cw);
    qkv_kernel<<<1563, 256, 0, stream>>>(x, cw, Q, K, V);      // 1563*64 >= 100000
    // persistent: 13 blocks/CU (LDS-limited) x 256 CUs
    attn_kernel<<<3328, 128, 0, stream>>>(p, idx, x, cw, Q, K, V, d_out);
}